// Round 17
// baseline (229.143 us; speedup 1.0000x reference)
//
#include <hip/hip_runtime.h>
#include <math.h>

// Causal self-attention, B=4, T=2048, E=1024, H=16, D=64. fp32 in/out,
// bf16 MFMA internally. r17 = r16 with the attn launch re-shaped for a
// real dispatch queue: 4-wave blocks, 64-row supertile, KVBLK=64 (32KB LDS
// -> 5 blocks/CU), 2048 blocks heavy-first (grid ~1.6x resident capacity).

typedef __bf16 bf16x8 __attribute__((ext_vector_type(8)));
typedef float f32x4 __attribute__((ext_vector_type(4)));
typedef unsigned int u32x4 __attribute__((ext_vector_type(4)));
typedef unsigned int uint;
typedef unsigned short ushort;

#define B_ 4
#define T_ 2048
#define E_ 1024
#define H_ 16
#define D_ 64
#define BT_ (B_ * T_)   // 8192

__device__ __forceinline__ f32x4 mfma16(bf16x8 a, bf16x8 b, f32x4 c) {
  return __builtin_amdgcn_mfma_f32_16x16x32_bf16(a, b, c, 0, 0, 0);
}

// async global->LDS, 16B per lane. LDS dest linear: base + lane*16.
__device__ __forceinline__ void gl_lds16(void* lds, const void* g) {
  __builtin_amdgcn_global_load_lds(
      (__attribute__((address_space(1))) unsigned int*)g,
      (__attribute__((address_space(3))) unsigned int*)lds, 16, 0, 0);
}

__device__ __forceinline__ uint pkbf(float a, float b) {
  ushort ux = __builtin_bit_cast(ushort, (__bf16)a);
  ushort uy = __builtin_bit_cast(ushort, (__bf16)b);
  return (uint)ux | ((uint)uy << 16);
}

// 1/sqrt(D) * log2(e), folded into the Q projection epilogue.
#define QSCL 0.18033688011112f

// ---------------------------------------------------------------- convert
// One launch for x (4096 blocks) + the four weight matrices (4 x 512).
__global__ __launch_bounds__(256) void cvt_all(const float* __restrict__ x,
                                               const float* __restrict__ w0,
                                               const float* __restrict__ w1,
                                               const float* __restrict__ w2,
                                               const float* __restrict__ w3,
                                               __bf16* __restrict__ xo,
                                               __bf16* __restrict__ o0,
                                               __bf16* __restrict__ o1,
                                               __bf16* __restrict__ o2,
                                               __bf16* __restrict__ o3) {
  const float* in;
  __bf16* out;
  int i;
  if (blockIdx.x < 4096) {
    in = x; out = xo;
    i = (blockIdx.x * 256 + threadIdx.x) * 8;
  } else {
    const int wb = blockIdx.x - 4096;
    switch (wb >> 9) {
      case 0: in = w0; out = o0; break;
      case 1: in = w1; out = o1; break;
      case 2: in = w2; out = o2; break;
      default: in = w3; out = o3; break;
    }
    i = ((wb & 511) * 256 + threadIdx.x) * 8;
  }
  float4 a = *(const float4*)&in[i];
  float4 b = *(const float4*)&in[i + 4];
  bf16x8 o;
  o[0] = (__bf16)a.x; o[1] = (__bf16)a.y; o[2] = (__bf16)a.z; o[3] = (__bf16)a.w;
  o[4] = (__bf16)b.x; o[5] = (__bf16)b.y; o[6] = (__bf16)b.z; o[7] = (__bf16)b.w;
  *(bf16x8*)&out[i] = o;
}

// ---------------------------------------------------------------- GEMM (NT)
// r12 structure: 128^2 tile, 4 waves, BK=32, single-buffer 2-barrier loop.
// Output projection: C[m][n] = sum_k A[m][k]*B[n][k] + bias[n], fp32 out.
// Grid (64, 8): x = m-tile so n-blocks sharing an A-panel land on one XCD.
__global__ __launch_bounds__(256) void gemm_out(const __bf16* __restrict__ A,
                                                const __bf16* __restrict__ Bm,
                                                const float* __restrict__ bias,
                                                float* __restrict__ out,
                                                int M, int N, int K) {
  __shared__ __bf16 sA[128 * 32];
  __shared__ __bf16 sB[128 * 32];
  const int tid = threadIdx.x;
  const int lane = tid & 63;
  const int wv = tid >> 6;
  const int wr = (wv >> 1) << 6;
  const int wc = (wv & 1) << 6;
  const int fr = lane & 15;
  const int fo = (lane >> 4) << 3;
  const int g = lane >> 4;
  const int m0 = blockIdx.x * 128;
  const int n0 = blockIdx.y * 128;

  f32x4 acc[4][4] = {};

  const __bf16* aRow = A + (size_t)(m0 + (tid >> 2)) * K + ((tid & 3) << 3);
  const __bf16* bRow = Bm + (size_t)(n0 + (tid >> 2)) * K + ((tid & 3) << 3);

  for (int kt = 0; kt < K; kt += 32) {
    gl_lds16(&sA[(size_t)tid * 8], aRow + kt);
    gl_lds16(&sA[(size_t)(256 + tid) * 8], aRow + (size_t)64 * K + kt);
    gl_lds16(&sB[(size_t)tid * 8], bRow + kt);
    gl_lds16(&sB[(size_t)(256 + tid) * 8], bRow + (size_t)64 * K + kt);
    __syncthreads();
    bf16x8 af[4], bq[4];
#pragma unroll
    for (int i = 0; i < 4; i++) af[i] = *(const bf16x8*)&sA[(wr + i * 16 + fr) * 32 + fo];
#pragma unroll
    for (int i = 0; i < 4; i++) bq[i] = *(const bf16x8*)&sB[(wc + i * 16 + fr) * 32 + fo];
#pragma unroll
    for (int i = 0; i < 4; i++)
#pragma unroll
      for (int j = 0; j < 4; j++) acc[i][j] = mfma16(af[i], bq[j], acc[i][j]);
    __syncthreads();
  }

#pragma unroll
  for (int i = 0; i < 4; i++) {
#pragma unroll
    for (int j = 0; j < 4; j++) {
#pragma unroll
      for (int r = 0; r < 4; r++) {
        const int m = m0 + wr + i * 16 + g * 4 + r;
        const int n = n0 + wc + j * 16 + fr;
        out[(size_t)m * N + n] = acc[i][j][r] + bias[n];
      }
    }
  }
}

// Fused QKV projections: grid (64, 8, 3); x = token-tile so blocks sharing
// an x-panel land on the same XCD.
// z=0: Q = (x Wq^T + bq) * QSCL -> bf16 scatter [B,H,T,D]  (scale folded)
// z=1: K = x Wk^T + bk          -> bf16 scatter [B,H,T,D]
// z=2: V^T = Wv x^T + bv        -> bf16 scatter [B,H,D,T]  (operands swapped)
__global__ __launch_bounds__(256) void gemm_qkv(const __bf16* __restrict__ xb,
                                                const __bf16* __restrict__ Wq,
                                                const __bf16* __restrict__ Wk,
                                                const __bf16* __restrict__ Wv,
                                                const float* __restrict__ bq,
                                                const float* __restrict__ bk,
                                                const float* __restrict__ bv,
                                                __bf16* __restrict__ Qb,
                                                __bf16* __restrict__ Kb,
                                                __bf16* __restrict__ Vtb) {
  __shared__ __bf16 sA[128 * 32];
  __shared__ __bf16 sB[128 * 32];
  const int z = blockIdx.z;
  const __bf16* A;
  const __bf16* Bm;
  const float* bias;
  int m0, n0;
  if (z == 0) {
    A = xb; Bm = Wq; bias = bq;
    m0 = blockIdx.x * 128; n0 = blockIdx.y * 128;
  } else if (z == 1) {
    A = xb; Bm = Wk; bias = bk;
    m0 = blockIdx.x * 128; n0 = blockIdx.y * 128;
  } else {
    A = Wv; Bm = xb; bias = bv;           // V^T: m = embed, n = token
    m0 = blockIdx.y * 128; n0 = blockIdx.x * 128;
  }
  const int K = E_;
  const int tid = threadIdx.x;
  const int lane = tid & 63;
  const int wv = tid >> 6;
  const int wr = (wv >> 1) << 6;
  const int wc = (wv & 1) << 6;
  const int fr = lane & 15;
  const int fo = (lane >> 4) << 3;
  const int g = lane >> 4;

  f32x4 acc[4][4] = {};

  const __bf16* aRow = A + (size_t)(m0 + (tid >> 2)) * K + ((tid & 3) << 3);
  const __bf16* bRow = Bm + (size_t)(n0 + (tid >> 2)) * K + ((tid & 3) << 3);

  for (int kt = 0; kt < K; kt += 32) {
    gl_lds16(&sA[(size_t)tid * 8], aRow + kt);
    gl_lds16(&sA[(size_t)(256 + tid) * 8], aRow + (size_t)64 * K + kt);
    gl_lds16(&sB[(size_t)tid * 8], bRow + kt);
    gl_lds16(&sB[(size_t)(256 + tid) * 8], bRow + (size_t)64 * K + kt);
    __syncthreads();
    bf16x8 af[4], bq4[4];
#pragma unroll
    for (int i = 0; i < 4; i++) af[i] = *(const bf16x8*)&sA[(wr + i * 16 + fr) * 32 + fo];
#pragma unroll
    for (int i = 0; i < 4; i++) bq4[i] = *(const bf16x8*)&sB[(wc + i * 16 + fr) * 32 + fo];
#pragma unroll
    for (int i = 0; i < 4; i++)
#pragma unroll
      for (int j = 0; j < 4; j++) acc[i][j] = mfma16(af[i], bq4[j], acc[i][j]);
    __syncthreads();
  }

#pragma unroll
  for (int i = 0; i < 4; i++) {
#pragma unroll
    for (int j = 0; j < 4; j++) {
#pragma unroll
      for (int r = 0; r < 4; r++) {
        const int m = m0 + wr + i * 16 + g * 4 + r;
        const int n = n0 + wc + j * 16 + fr;
        float v = acc[i][j][r];
        if (z == 2) {
          v += bias[m];
          const int b = n >> 11, t = n & (T_ - 1);
          const int h = m >> 6, d = m & 63;
          Vtb[(((size_t)b * H_ + h) * D_ + d) * T_ + t] = (__bf16)v;
        } else {
          v += bias[n];
          if (z == 0) v *= QSCL;  // fold softmax scale into Q
          const int b = m >> 11, t = m & (T_ - 1);
          const int h = n >> 6, d = n & 63;
          __bf16* out = (z == 0) ? Qb : Kb;
          out[(((size_t)b * H_ + h) * T_ + t) * D_ + d] = (__bf16)v;
        }
      }
    }
  }
}

// ---------------------------------------------------------------- attention
// Q,K: [B,H,T,D] bf16 (Q pre-scaled by QSCL).  Vt: [B,H,D,T] bf16.
// O: [B,T,H,D] bf16.
// r11's verified KVBLK=64 compute body, re-launched for queue smoothing:
// 4 waves x 16 q-rows = 64-row supertile, 2048 blocks (64 bh x 32
// supertiles) heavy-first (s = 31-(j&31)); LDS 32KB -> 5 blocks/CU resident
// (20 waves/CU) with a ~1.6x dispatch queue, vs r16's 512-block grid that
// hard-capped residency at 2 blocks/CU. Head->XCD pinning kept (bh%8==k&7).
// K/V staged once per block (XOR-chunk swizzle both sides, rule #21),
// swapped QK^T, partial-vote defer-max, bpermute P-redistribution.
__global__ __launch_bounds__(256) void attn_fwd(const __bf16* __restrict__ Q,
                                                const __bf16* __restrict__ Kg,
                                                const __bf16* __restrict__ Vt,
                                                __bf16* __restrict__ O) {
  __shared__ __bf16 sK[2][64 * 64];  // [kv][d], chunk-swizzled (8KB each)
  __shared__ __bf16 sV[2][64 * 64];  // [d][kv], chunk-swizzled (8KB each)
  const int tid = threadIdx.x;
  const int lane = tid & 63;
  const int wv = tid >> 6;  // wave 0..3 -> q rows 16*wv..+16 of the supertile
  const int fr = lane & 15;
  const int g = lane >> 4;
  const int k = blockIdx.x;
  const int j = k >> 3;
  const int bh = (k & 7) + ((j >> 5) << 3);  // head pinned to xcd = bh%8
  const int s = 31 - (j & 31);               // heavy supertiles dispatch first
  const __bf16* Qp = Q + (size_t)bh * T_ * D_;
  const __bf16* Kp = Kg + (size_t)bh * T_ * D_;
  const __bf16* Vp = Vt + (size_t)bh * D_ * T_;
  const int addrA = (fr + 32 * (g & 1)) * 4;  // bpermute base (bytes)
  const int swz = fr & 7;
  const int b = bh >> 4, h = bh & 15;

  // cooperative stage of one 64-kv tile (K [64][64], V^T [64][64]);
  // 2 x 512 items x 16B over 256 threads; pre-swizzled global source.
  auto stage = [&](int buf, int kv0) {
#pragma unroll
    for (int rr = 0; rr < 2; ++rr) {
      const int idx = rr * 256 + tid;  // 0..511
      const int row = idx >> 3, ch = idx & 7;
      gl_lds16(&sK[buf][idx * 8],
               Kp + (size_t)(kv0 + row) * D_ + ((ch ^ (row & 7)) << 3));
      gl_lds16(&sV[buf][idx * 8],
               Vp + (size_t)row * T_ + kv0 + ((ch ^ (row & 7)) << 3));
    }
  };

  const int qw = s * 64 + wv * 16;  // this wave's 16-row q base
  const int ntile = s + 1;          // 64-kv tiles

  // Q B-frags: lane holds Q[qw+fr][kc*32 + g*8 + j]
  bf16x8 qf[2];
#pragma unroll
  for (int kc = 0; kc < 2; kc++)
    qf[kc] = *(const bf16x8*)&Qp[(size_t)(qw + fr) * D_ + kc * 32 + g * 8];

  f32x4 acc[4] = {};       // O[q=qw+g*4+r][d=nd*16+fr]
  float mrun = -INFINITY;  // per-lane q-row (fr) stats
  float lrun = 0.f;

  stage(0, 0);
  __syncthreads();
  int cur = 0;

#pragma unroll 1
  for (int kt = 0; kt < ntile; ++kt) {
    const int kv0 = kt << 6;
    if (kt + 1 < ntile) stage(cur ^ 1, (kt + 1) << 6);  // prefetch next

    // ---- S^T = K . Q^T  (K frags from swizzled LDS)
    f32x4 st[4] = {};  // [kvf]: S^T[kv=kv0+kvf*16+g*4+r][q=qw+fr]
    __builtin_amdgcn_s_setprio(1);
#pragma unroll
    for (int kvf = 0; kvf < 4; ++kvf) {
      const int row = kvf * 16 + fr;
      bf16x8 kf0 = *(const bf16x8*)&sK[cur][row * 64 + ((g ^ swz) << 3)];
      bf16x8 kf1 = *(const bf16x8*)&sK[cur][row * 64 + (((g + 4) ^ swz) << 3)];
      st[kvf] = mfma16(kf0, qf[0], st[kvf]);
      st[kvf] = mfma16(kf1, qf[1], st[kvf]);
    }
    __builtin_amdgcn_s_setprio(0);

    // ---- causal mask (only the last tile straddles this wave's rows)
    if (kt == ntile - 1) {
#pragma unroll
      for (int kvf = 0; kvf < 4; ++kvf)
#pragma unroll
        for (int r = 0; r < 4; ++r)
          if (kv0 + kvf * 16 + g * 4 + r > qw + fr) st[kvf][r] = -INFINITY;
    }

    // ---- online softmax (per-lane row; Q pre-scaled so st is in log2)
    float rm[4];
#pragma unroll
    for (int kvf = 0; kvf < 4; ++kvf)
      rm[kvf] =
          fmaxf(fmaxf(st[kvf][0], st[kvf][1]), fmaxf(st[kvf][2], st[kvf][3]));
    float rmax = fmaxf(fmaxf(rm[0], rm[1]), fmaxf(rm[2], rm[3]));

    // defer-max fast path: partial-max vote, no cross-lane ops
    if (!__all(rmax - mrun <= 8.f)) {
      float rfull = fmaxf(rmax, __shfl_xor(rmax, 16, 64));
      rfull = fmaxf(rfull, __shfl_xor(rfull, 32, 64));
      const float mn = fmaxf(mrun, rfull);
      const float corr = exp2f(mrun - mn);  // 0 on first tile
      mrun = mn;
      lrun *= corr;
      float cg[4];
#pragma unroll
      for (int r = 0; r < 4; ++r) cg[r] = __shfl(corr, g * 4 + r, 64);
#pragma unroll
      for (int nd = 0; nd < 4; ++nd)
#pragma unroll
        for (int r = 0; r < 4; ++r) acc[nd][r] *= cg[r];
    }

    float p[4][4];
    float ls = 0.f;
#pragma unroll
    for (int kvf = 0; kvf < 4; ++kvf)
#pragma unroll
      for (int r = 0; r < 4; ++r) {
        p[kvf][r] = exp2f(st[kvf][r] - mrun);
        ls += p[kvf][r];
      }
    lrun += ls;

    uint w[4][2];
#pragma unroll
    for (int kvf = 0; kvf < 4; ++kvf) {
      w[kvf][0] = pkbf(p[kvf][0], p[kvf][1]);
      w[kvf][1] = pkbf(p[kvf][2], p[kvf][3]);
    }
    // redistribute to A-frag: lane needs kv = 32kc + 8g + 2m (,+1)
    uint W[2][4];
#pragma unroll
    for (int kc = 0; kc < 2; ++kc)
#pragma unroll
      for (int m = 0; m < 4; ++m) {
        const int a = addrA + (m >> 1) * 64;
        int t0 = __builtin_amdgcn_ds_bpermute(a, (int)w[2 * kc][m & 1]);
        int t1 = __builtin_amdgcn_ds_bpermute(a, (int)w[2 * kc + 1][m & 1]);
        W[kc][m] = (uint)((g >> 1) ? t1 : t0);
      }

    // ---- O += P V  (V frags from swizzled LDS)
    __builtin_amdgcn_s_setprio(1);
#pragma unroll
    for (int kc = 0; kc < 2; ++kc) {
      u32x4 t;
      t[0] = W[kc][0]; t[1] = W[kc][1]; t[2] = W[kc][2]; t[3] = W[kc][3];
      bf16x8 pa = __builtin_bit_cast(bf16x8, t);
#pragma unroll
      for (int nd = 0; nd < 4; ++nd) {
        const int row = nd * 16 + fr;
        bf16x8 vf =
            *(const bf16x8*)&sV[cur][row * 64 + (((4 * kc + g) ^ swz) << 3)];
        acc[nd] = mfma16(pa, vf, acc[nd]);
      }
    }
    __builtin_amdgcn_s_setprio(0);

    __syncthreads();  // drains stage vmcnt + protects buffer swap
    cur ^= 1;
  }

  // ---- epilogue: full row sums, divide, store [B,T,H,D]
  lrun += __shfl_xor(lrun, 16, 64);
  lrun += __shfl_xor(lrun, 32, 64);
  float linv[4];
#pragma unroll
  for (int r = 0; r < 4; ++r) linv[r] = 1.f / __shfl(lrun, g * 4 + r, 64);
#pragma unroll
  for (int nd = 0; nd < 4; ++nd)
#pragma unroll
    for (int r = 0; r < 4; ++r) {
      const int t = qw + g * 4 + r;
      O[(((size_t)b * T_ + t) * H_ + h) * D_ + nd * 16 + fr] =
          (__bf16)(acc[nd][r] * linv[r]);
    }
}

// ---------------------------------------------------------------- launcher
extern "C" void kernel_launch(void* const* d_in, const int* in_sizes, int n_in,
                              void* d_out, int out_size, void* d_ws, size_t ws_size,
                              hipStream_t stream) {
  const float* x  = (const float*)d_in[0];
  const float* Wq = (const float*)d_in[1];
  const float* bq = (const float*)d_in[2];
  const float* Wk = (const float*)d_in[3];
  const float* bk = (const float*)d_in[4];
  const float* Wv = (const float*)d_in[5];
  const float* bv = (const float*)d_in[6];
  const float* Wo = (const float*)d_in[7];
  const float* bo = (const float*)d_in[8];

  char* w = (char*)d_ws;
  __bf16* xb  = (__bf16*)w; w += (size_t)BT_ * E_ * 2;
  __bf16* Wqb = (__bf16*)w; w += (size_t)E_ * E_ * 2;
  __bf16* Wkb = (__bf16*)w; w += (size_t)E_ * E_ * 2;
  __bf16* Wvb = (__bf16*)w; w += (size_t)E_ * E_ * 2;
  __bf16* Wob = (__bf16*)w; w += (size_t)E_ * E_ * 2;
  __bf16* Qb  = (__bf16*)w; w += (size_t)BT_ * E_ * 2;
  __bf16* Kb  = (__bf16*)w; w += (size_t)BT_ * E_ * 2;
  __bf16* Vtb = (__bf16*)w; w += (size_t)BT_ * E_ * 2;
  __bf16* Ob  = (__bf16*)w; w += (size_t)BT_ * E_ * 2;

  cvt_all<<<4096 + 2048, 256, 0, stream>>>(x, Wq, Wk, Wv, Wo,
                                           xb, Wqb, Wkb, Wvb, Wob);

  gemm_qkv<<<dim3(BT_ / 128, E_ / 128, 3), 256, 0, stream>>>(
      xb, Wqb, Wkb, Wvb, bq, bk, bv, Qb, Kb, Vtb);

  attn_fwd<<<2048, 256, 0, stream>>>(Qb, Kb, Vtb, Ob);

  gemm_out<<<dim3(BT_ / 128, E_ / 128), 256, 0, stream>>>(
      Ob, Wob, bo, (float*)d_out, BT_, E_, E_);
}

// Round 18
// 201.807 us; speedup vs baseline: 1.1355x; 1.1355x over previous
//
#include <hip/hip_runtime.h>
#include <math.h>

// Causal self-attention, B=4, T=2048, E=1024, H=16, D=64. fp32 in/out,
// bf16 MFMA internally. r18 = r16 exact restore (best measured: 200.9 µs).
// r17's queue-shaped attn launch regressed (third failed occupancy-via-grid
// attempt); the paired-uniform 512-block x 8-wave schedule is the measured
// optimum of this structure family.

typedef __bf16 bf16x8 __attribute__((ext_vector_type(8)));
typedef float f32x4 __attribute__((ext_vector_type(4)));
typedef unsigned int u32x4 __attribute__((ext_vector_type(4)));
typedef unsigned int uint;
typedef unsigned short ushort;

#define B_ 4
#define T_ 2048
#define E_ 1024
#define H_ 16
#define D_ 64
#define BT_ (B_ * T_)   // 8192

__device__ __forceinline__ f32x4 mfma16(bf16x8 a, bf16x8 b, f32x4 c) {
  return __builtin_amdgcn_mfma_f32_16x16x32_bf16(a, b, c, 0, 0, 0);
}

// async global->LDS, 16B per lane. LDS dest linear: base + lane*16.
__device__ __forceinline__ void gl_lds16(void* lds, const void* g) {
  __builtin_amdgcn_global_load_lds(
      (__attribute__((address_space(1))) unsigned int*)g,
      (__attribute__((address_space(3))) unsigned int*)lds, 16, 0, 0);
}

__device__ __forceinline__ uint pkbf(float a, float b) {
  ushort ux = __builtin_bit_cast(ushort, (__bf16)a);
  ushort uy = __builtin_bit_cast(ushort, (__bf16)b);
  return (uint)ux | ((uint)uy << 16);
}

// 1/sqrt(D) * log2(e), folded into the Q projection epilogue.
#define QSCL 0.18033688011112f

// ---------------------------------------------------------------- convert
// One launch for x (4096 blocks) + the four weight matrices (4 x 512).
__global__ __launch_bounds__(256) void cvt_all(const float* __restrict__ x,
                                               const float* __restrict__ w0,
                                               const float* __restrict__ w1,
                                               const float* __restrict__ w2,
                                               const float* __restrict__ w3,
                                               __bf16* __restrict__ xo,
                                               __bf16* __restrict__ o0,
                                               __bf16* __restrict__ o1,
                                               __bf16* __restrict__ o2,
                                               __bf16* __restrict__ o3) {
  const float* in;
  __bf16* out;
  int i;
  if (blockIdx.x < 4096) {
    in = x; out = xo;
    i = (blockIdx.x * 256 + threadIdx.x) * 8;
  } else {
    const int wb = blockIdx.x - 4096;
    switch (wb >> 9) {
      case 0: in = w0; out = o0; break;
      case 1: in = w1; out = o1; break;
      case 2: in = w2; out = o2; break;
      default: in = w3; out = o3; break;
    }
    i = ((wb & 511) * 256 + threadIdx.x) * 8;
  }
  float4 a = *(const float4*)&in[i];
  float4 b = *(const float4*)&in[i + 4];
  bf16x8 o;
  o[0] = (__bf16)a.x; o[1] = (__bf16)a.y; o[2] = (__bf16)a.z; o[3] = (__bf16)a.w;
  o[4] = (__bf16)b.x; o[5] = (__bf16)b.y; o[6] = (__bf16)b.z; o[7] = (__bf16)b.w;
  *(bf16x8*)&out[i] = o;
}

// ---------------------------------------------------------------- GEMM (NT)
// r12 structure: 128^2 tile, 4 waves, BK=32, single-buffer 2-barrier loop
// (implicit cross-block overlap at ~4 blocks/CU covers the drain; dbuf,
// 32x32-MFMA and 256^2 8-phase variants all measured worse at this shape).
// Output projection: C[m][n] = sum_k A[m][k]*B[n][k] + bias[n], fp32 out.
// Grid (64, 8): x = m-tile so n-blocks sharing an A-panel land on one XCD.
__global__ __launch_bounds__(256) void gemm_out(const __bf16* __restrict__ A,
                                                const __bf16* __restrict__ Bm,
                                                const float* __restrict__ bias,
                                                float* __restrict__ out,
                                                int M, int N, int K) {
  __shared__ __bf16 sA[128 * 32];
  __shared__ __bf16 sB[128 * 32];
  const int tid = threadIdx.x;
  const int lane = tid & 63;
  const int wv = tid >> 6;
  const int wr = (wv >> 1) << 6;
  const int wc = (wv & 1) << 6;
  const int fr = lane & 15;
  const int fo = (lane >> 4) << 3;
  const int g = lane >> 4;
  const int m0 = blockIdx.x * 128;
  const int n0 = blockIdx.y * 128;

  f32x4 acc[4][4] = {};

  const __bf16* aRow = A + (size_t)(m0 + (tid >> 2)) * K + ((tid & 3) << 3);
  const __bf16* bRow = Bm + (size_t)(n0 + (tid >> 2)) * K + ((tid & 3) << 3);

  for (int kt = 0; kt < K; kt += 32) {
    gl_lds16(&sA[(size_t)tid * 8], aRow + kt);
    gl_lds16(&sA[(size_t)(256 + tid) * 8], aRow + (size_t)64 * K + kt);
    gl_lds16(&sB[(size_t)tid * 8], bRow + kt);
    gl_lds16(&sB[(size_t)(256 + tid) * 8], bRow + (size_t)64 * K + kt);
    __syncthreads();
    bf16x8 af[4], bq[4];
#pragma unroll
    for (int i = 0; i < 4; i++) af[i] = *(const bf16x8*)&sA[(wr + i * 16 + fr) * 32 + fo];
#pragma unroll
    for (int i = 0; i < 4; i++) bq[i] = *(const bf16x8*)&sB[(wc + i * 16 + fr) * 32 + fo];
#pragma unroll
    for (int i = 0; i < 4; i++)
#pragma unroll
      for (int j = 0; j < 4; j++) acc[i][j] = mfma16(af[i], bq[j], acc[i][j]);
    __syncthreads();
  }

#pragma unroll
  for (int i = 0; i < 4; i++) {
#pragma unroll
    for (int j = 0; j < 4; j++) {
#pragma unroll
      for (int r = 0; r < 4; r++) {
        const int m = m0 + wr + i * 16 + g * 4 + r;
        const int n = n0 + wc + j * 16 + fr;
        out[(size_t)m * N + n] = acc[i][j][r] + bias[n];
      }
    }
  }
}

// Fused QKV projections: grid (64, 8, 3); x = token-tile so blocks sharing
// an x-panel land on the same XCD.
// z=0: Q = (x Wq^T + bq) * QSCL -> bf16 scatter [B,H,T,D]  (scale folded)
// z=1: K = x Wk^T + bk          -> bf16 scatter [B,H,T,D]
// z=2: V^T = Wv x^T + bv        -> bf16 scatter [B,H,D,T]  (operands swapped)
__global__ __launch_bounds__(256) void gemm_qkv(const __bf16* __restrict__ xb,
                                                const __bf16* __restrict__ Wq,
                                                const __bf16* __restrict__ Wk,
                                                const __bf16* __restrict__ Wv,
                                                const float* __restrict__ bq,
                                                const float* __restrict__ bk,
                                                const float* __restrict__ bv,
                                                __bf16* __restrict__ Qb,
                                                __bf16* __restrict__ Kb,
                                                __bf16* __restrict__ Vtb) {
  __shared__ __bf16 sA[128 * 32];
  __shared__ __bf16 sB[128 * 32];
  const int z = blockIdx.z;
  const __bf16* A;
  const __bf16* Bm;
  const float* bias;
  int m0, n0;
  if (z == 0) {
    A = xb; Bm = Wq; bias = bq;
    m0 = blockIdx.x * 128; n0 = blockIdx.y * 128;
  } else if (z == 1) {
    A = xb; Bm = Wk; bias = bk;
    m0 = blockIdx.x * 128; n0 = blockIdx.y * 128;
  } else {
    A = Wv; Bm = xb; bias = bv;           // V^T: m = embed, n = token
    m0 = blockIdx.y * 128; n0 = blockIdx.x * 128;
  }
  const int K = E_;
  const int tid = threadIdx.x;
  const int lane = tid & 63;
  const int wv = tid >> 6;
  const int wr = (wv >> 1) << 6;
  const int wc = (wv & 1) << 6;
  const int fr = lane & 15;
  const int fo = (lane >> 4) << 3;
  const int g = lane >> 4;

  f32x4 acc[4][4] = {};

  const __bf16* aRow = A + (size_t)(m0 + (tid >> 2)) * K + ((tid & 3) << 3);
  const __bf16* bRow = Bm + (size_t)(n0 + (tid >> 2)) * K + ((tid & 3) << 3);

  for (int kt = 0; kt < K; kt += 32) {
    gl_lds16(&sA[(size_t)tid * 8], aRow + kt);
    gl_lds16(&sA[(size_t)(256 + tid) * 8], aRow + (size_t)64 * K + kt);
    gl_lds16(&sB[(size_t)tid * 8], bRow + kt);
    gl_lds16(&sB[(size_t)(256 + tid) * 8], bRow + (size_t)64 * K + kt);
    __syncthreads();
    bf16x8 af[4], bq4[4];
#pragma unroll
    for (int i = 0; i < 4; i++) af[i] = *(const bf16x8*)&sA[(wr + i * 16 + fr) * 32 + fo];
#pragma unroll
    for (int i = 0; i < 4; i++) bq4[i] = *(const bf16x8*)&sB[(wc + i * 16 + fr) * 32 + fo];
#pragma unroll
    for (int i = 0; i < 4; i++)
#pragma unroll
      for (int j = 0; j < 4; j++) acc[i][j] = mfma16(af[i], bq4[j], acc[i][j]);
    __syncthreads();
  }

#pragma unroll
  for (int i = 0; i < 4; i++) {
#pragma unroll
    for (int j = 0; j < 4; j++) {
#pragma unroll
      for (int r = 0; r < 4; r++) {
        const int m = m0 + wr + i * 16 + g * 4 + r;
        const int n = n0 + wc + j * 16 + fr;
        float v = acc[i][j][r];
        if (z == 2) {
          v += bias[m];
          const int b = n >> 11, t = n & (T_ - 1);
          const int h = m >> 6, d = m & 63;
          Vtb[(((size_t)b * H_ + h) * D_ + d) * T_ + t] = (__bf16)v;
        } else {
          v += bias[n];
          if (z == 0) v *= QSCL;  // fold softmax scale into Q
          const int b = m >> 11, t = m & (T_ - 1);
          const int h = n >> 6, d = n & 63;
          __bf16* out = (z == 0) ? Qb : Kb;
          out[(((size_t)b * H_ + h) * T_ + t) * D_ + d] = (__bf16)v;
        }
      }
    }
  }
}

// ---------------------------------------------------------------- attention
// r12 attn verbatim (90.4 µs measured). Q,K: [B,H,T,D] bf16 (Q pre-scaled
// by QSCL). Vt: [B,H,D,T]. 8 waves x 16 q-rows, 512 paired blocks
// (supertile pair pr,15-pr), KVBLK=128, K/V staged once per block
// (XOR-chunk swizzle, rule #21), head->XCD pinning, swapped QK^T,
// partial-vote defer-max, bpermute P-redistribution.
__global__ __launch_bounds__(512) void attn_fwd(const __bf16* __restrict__ Q,
                                                const __bf16* __restrict__ Kg,
                                                const __bf16* __restrict__ Vt,
                                                __bf16* __restrict__ O) {
  __shared__ __bf16 sK[2][128 * 64];  // [kv][d], chunk-swizzled (16KB each)
  __shared__ __bf16 sV[2][64 * 128];  // [d][kv], chunk-swizzled (16KB each)
  const int tid = threadIdx.x;
  const int lane = tid & 63;
  const int wv = tid >> 6;  // wave 0..7 -> q rows 16*wv..+16 of the supertile
  const int fr = lane & 15;
  const int g = lane >> 4;
  const int k = blockIdx.x;
  const int bh = (k & 7) | ((k >> 6) << 3);  // head pinned to xcd = bh%8
  const int pr = (k >> 3) & 7;               // supertile pair index
  const __bf16* Qp = Q + (size_t)bh * T_ * D_;
  const __bf16* Kp = Kg + (size_t)bh * T_ * D_;
  const __bf16* Vp = Vt + (size_t)bh * D_ * T_;
  const int addrA = (fr + 32 * (g & 1)) * 4;  // bpermute base (bytes)
  const int b = bh >> 4, h = bh & 15;

  auto stage = [&](int buf, int kv0) {
#pragma unroll
    for (int rr = 0; rr < 2; ++rr) {
      const int idx = rr * 512 + tid;  // 0..1023
      const int krow = idx >> 3, kch = idx & 7;
      gl_lds16(&sK[buf][idx * 8],
               Kp + (size_t)(kv0 + krow) * D_ + ((kch ^ (krow & 7)) << 3));
      const int vrow = idx >> 4, vch = idx & 15;
      gl_lds16(&sV[buf][idx * 8],
               Vp + (size_t)vrow * T_ + kv0 + ((vch ^ (vrow & 15)) << 3));
    }
  };

#pragma unroll 1
  for (int pass = 0; pass < 2; ++pass) {
    const int s = pass ? 15 - pr : pr;   // supertile (128 q rows)
    const int qw = s * 128 + wv * 16;    // this wave's 16-row q base
    const int ntile = s + 1;             // 128-kv tiles

    // Q B-frags: lane holds Q[qw+fr][kc*32 + g*8 + j]
    bf16x8 qf[2];
#pragma unroll
    for (int kc = 0; kc < 2; kc++)
      qf[kc] = *(const bf16x8*)&Qp[(size_t)(qw + fr) * D_ + kc * 32 + g * 8];

    f32x4 acc[4] = {};       // O[q=qw+g*4+r][d=nd*16+fr]
    float mrun = -INFINITY;  // per-lane q-row (fr) stats
    float lrun = 0.f;

    stage(0, 0);
    __syncthreads();
    int cur = 0;

#pragma unroll 1
    for (int kt = 0; kt < ntile; ++kt) {
      const int kv0 = kt << 7;
      if (kt + 1 < ntile) stage(cur ^ 1, (kt + 1) << 7);  // prefetch next

      // ---- S^T = K . Q^T  (K frags from swizzled LDS)
      f32x4 st[8] = {};  // [kvf]: S^T[kv=kv0+kvf*16+g*4+r][q=qw+fr]
      __builtin_amdgcn_s_setprio(1);
#pragma unroll
      for (int kvf = 0; kvf < 8; ++kvf) {
        const int row = kvf * 16 + fr;
        bf16x8 kf0 = *(const bf16x8*)&sK[cur][row * 64 + ((g ^ (fr & 7)) << 3)];
        bf16x8 kf1 =
            *(const bf16x8*)&sK[cur][row * 64 + (((g + 4) ^ (fr & 7)) << 3)];
        st[kvf] = mfma16(kf0, qf[0], st[kvf]);
        st[kvf] = mfma16(kf1, qf[1], st[kvf]);
      }
      __builtin_amdgcn_s_setprio(0);

      // ---- causal mask (only the last tile straddles this wave's rows)
      if (kv0 + 127 > qw) {
#pragma unroll
        for (int kvf = 0; kvf < 8; ++kvf)
#pragma unroll
          for (int r = 0; r < 4; ++r)
            if (kv0 + kvf * 16 + g * 4 + r > qw + fr) st[kvf][r] = -INFINITY;
      }

      // ---- online softmax (per-lane row; Q pre-scaled so st is in log2)
      float rm[8];
#pragma unroll
      for (int kvf = 0; kvf < 8; ++kvf)
        rm[kvf] =
            fmaxf(fmaxf(st[kvf][0], st[kvf][1]), fmaxf(st[kvf][2], st[kvf][3]));
      float rmax = fmaxf(fmaxf(fmaxf(rm[0], rm[1]), fmaxf(rm[2], rm[3])),
                         fmaxf(fmaxf(rm[4], rm[5]), fmaxf(rm[6], rm[7])));

      // defer-max fast path: partial-max vote, no cross-lane ops
      if (!__all(rmax - mrun <= 8.f)) {
        float rfull = fmaxf(rmax, __shfl_xor(rmax, 16, 64));
        rfull = fmaxf(rfull, __shfl_xor(rfull, 32, 64));
        const float mn = fmaxf(mrun, rfull);
        const float corr = exp2f(mrun - mn);  // 0 on first tile
        mrun = mn;
        lrun *= corr;
        float cg[4];
#pragma unroll
        for (int r = 0; r < 4; ++r) cg[r] = __shfl(corr, g * 4 + r, 64);
#pragma unroll
        for (int nd = 0; nd < 4; ++nd)
#pragma unroll
          for (int r = 0; r < 4; ++r) acc[nd][r] *= cg[r];
      }

      float p[8][4];
      float ls = 0.f;
#pragma unroll
      for (int kvf = 0; kvf < 8; ++kvf)
#pragma unroll
        for (int r = 0; r < 4; ++r) {
          p[kvf][r] = exp2f(st[kvf][r] - mrun);
          ls += p[kvf][r];
        }
      lrun += ls;

      uint w[8][2];
#pragma unroll
      for (int kvf = 0; kvf < 8; ++kvf) {
        w[kvf][0] = pkbf(p[kvf][0], p[kvf][1]);
        w[kvf][1] = pkbf(p[kvf][2], p[kvf][3]);
      }
      // redistribute to A-frag: lane needs kv = 32kc + 8g + 2m (,+1)
      uint W[4][4];
#pragma unroll
      for (int kc = 0; kc < 4; ++kc)
#pragma unroll
        for (int m = 0; m < 4; ++m) {
          const int a = addrA + (m >> 1) * 64;
          int t0 = __builtin_amdgcn_ds_bpermute(a, (int)w[2 * kc][m & 1]);
          int t1 = __builtin_amdgcn_ds_bpermute(a, (int)w[2 * kc + 1][m & 1]);
          W[kc][m] = (uint)((g >> 1) ? t1 : t0);
        }

      // ---- O += P V  (V frags from swizzled LDS)
      __builtin_amdgcn_s_setprio(1);
#pragma unroll
      for (int kc = 0; kc < 4; ++kc) {
        u32x4 t;
        t[0] = W[kc][0]; t[1] = W[kc][1]; t[2] = W[kc][2]; t[3] = W[kc][3];
        bf16x8 pa = __builtin_bit_cast(bf16x8, t);
#pragma unroll
        for (int nd = 0; nd < 4; ++nd) {
          const int row = nd * 16 + fr;
          bf16x8 vf =
              *(const bf16x8*)&sV[cur][row * 128 + (((4 * kc + g) ^ fr) << 3)];
          acc[nd] = mfma16(pa, vf, acc[nd]);
        }
      }
      __builtin_amdgcn_s_setprio(0);

      __syncthreads();  // drains stage vmcnt + protects buffer swap
      cur ^= 1;
    }

    // ---- epilogue: full row sums, divide, store [B,T,H,D]
    lrun += __shfl_xor(lrun, 16, 64);
    lrun += __shfl_xor(lrun, 32, 64);
    float linv[4];
#pragma unroll
    for (int r = 0; r < 4; ++r) linv[r] = 1.f / __shfl(lrun, g * 4 + r, 64);
#pragma unroll
    for (int nd = 0; nd < 4; ++nd)
#pragma unroll
      for (int r = 0; r < 4; ++r) {
        const int t = qw + g * 4 + r;
        O[(((size_t)b * T_ + t) * H_ + h) * D_ + nd * 16 + fr] =
            (__bf16)(acc[nd][r] * linv[r]);
      }
  }
}

// ---------------------------------------------------------------- launcher
extern "C" void kernel_launch(void* const* d_in, const int* in_sizes, int n_in,
                              void* d_out, int out_size, void* d_ws, size_t ws_size,
                              hipStream_t stream) {
  const float* x  = (const float*)d_in[0];
  const float* Wq = (const float*)d_in[1];
  const float* bq = (const float*)d_in[2];
  const float* Wk = (const float*)d_in[3];
  const float* bk = (const float*)d_in[4];
  const float* Wv = (const float*)d_in[5];
  const float* bv = (const float*)d_in[6];
  const float* Wo = (const float*)d_in[7];
  const float* bo = (const float*)d_in[8];

  char* w = (char*)d_ws;
  __bf16* xb  = (__bf16*)w; w += (size_t)BT_ * E_ * 2;
  __bf16* Wqb = (__bf16*)w; w += (size_t)E_ * E_ * 2;
  __bf16* Wkb = (__bf16*)w; w += (size_t)E_ * E_ * 2;
  __bf16* Wvb = (__bf16*)w; w += (size_t)E_ * E_ * 2;
  __bf16* Wob = (__bf16*)w; w += (size_t)E_ * E_ * 2;
  __bf16* Qb  = (__bf16*)w; w += (size_t)BT_ * E_ * 2;
  __bf16* Kb  = (__bf16*)w; w += (size_t)BT_ * E_ * 2;
  __bf16* Vtb = (__bf16*)w; w += (size_t)BT_ * E_ * 2;
  __bf16* Ob  = (__bf16*)w; w += (size_t)BT_ * E_ * 2;

  cvt_all<<<4096 + 2048, 256, 0, stream>>>(x, Wq, Wk, Wv, Wo,
                                           xb, Wqb, Wkb, Wvb, Wob);

  gemm_qkv<<<dim3(BT_ / 128, E_ / 128, 3), 256, 0, stream>>>(
      xb, Wqb, Wkb, Wvb, bq, bk, bv, Qb, Kb, Vtb);

  attn_fwd<<<512, 512, 0, stream>>>(Qb, Kb, Vtb, Ob);

  gemm_out<<<dim3(BT_ / 128, E_ / 128), 256, 0, stream>>>(
      Ob, Wob, bo, (float*)d_out, BT_, E_, E_);
}